// Round 3
// baseline (545.417 us; speedup 1.0000x reference)
//
#include <hip/hip_runtime.h>
#include <math.h>

#define TOKENS 16384
#define DD 4096
#define NE 64
#define MBLK 256      // tokens per k1 block
#define KB 32         // k-chunk

// ---- k0: transpose W[e][k] -> WT[k][e] (1 MB, once per launch) ----
__global__ void k0_transpose(const float* __restrict__ Wg, float* __restrict__ WT) {
  const int k0 = blockIdx.x * 64;
  const int e  = threadIdx.x & 63;
  const int kq = threadIdx.x >> 6;          // 0..3
#pragma unroll
  for (int kk = 0; kk < 16; ++kk) {
    const int k = k0 + kq * 16 + kk;
    WT[(long)k * NE + e] = Wg[(long)e * DD + k];
  }
}

// ---- k1: register-tiled fp32 GEMM: 8 tokens x 8 experts per lane ----
__global__ __launch_bounds__(256, 2)
void k1_gemm(const float* __restrict__ x, const float* __restrict__ WT,
             float* __restrict__ part, int kPerSlice) {
  __shared__ __align__(16) float xs[KB][260];  // [k][token], pad: writes 4-way max, reads 2-way
  __shared__ __align__(16) float wt[KB][68];   // [k][expert]

  const int nm   = TOKENS / MBLK;           // 64
  const int mblk = blockIdx.x % nm;
  const int s    = blockIdx.x / nm;
  const int tid  = threadIdx.x;
  const long t0  = (long)mblk * MBLK;
  const int k0   = s * kPerSlice;

  // staging assignments
  const int stok  = tid >> 3;               // 0..31 (+32j)
  const int skc   = (tid & 7) * 4;          // x: k-offset 0..28
  const int wrow  = tid >> 3;               // 0..31 (k row of chunk)
  const int wcol8 = (tid & 7) * 8;          // 0..56

  const float* xg = x + (t0 + stok) * (long)DD + k0 + skc;
  const float* wg = WT + (long)(k0 + wrow) * NE + wcol8;

  // compute assignments: lane = tg*... consecutive lanes vary expert-group
  const int lane = tid & 63;
  const int wid  = tid >> 6;                // wave tokens: wid*64..+63
  const int eg   = lane & 7;                // expert group (fast -> coalesced C store)
  const int tg   = lane >> 3;               // token group
  const int xoff = wid * 64 + tg * 8;
  const int eoff = eg * 8;

  float4 xr[8], wr0, wr1;
#pragma unroll
  for (int j = 0; j < 8; ++j)
    xr[j] = *(const float4*)(xg + (long)(32 * j) * DD);
  wr0 = *(const float4*)(wg);
  wr1 = *(const float4*)(wg + 4);

  float acc[8][8];
#pragma unroll
  for (int i = 0; i < 8; ++i)
#pragma unroll
    for (int j = 0; j < 8; ++j) acc[i][j] = 0.f;

  const int nchunk = kPerSlice / KB;
  for (int c = 0; c < nchunk; ++c) {
    // staged regs -> LDS (x transposed scalar, w float4)
#pragma unroll
    for (int j = 0; j < 8; ++j) {
      const int tok = stok + 32 * j;
      xs[skc + 0][tok] = xr[j].x;
      xs[skc + 1][tok] = xr[j].y;
      xs[skc + 2][tok] = xr[j].z;
      xs[skc + 3][tok] = xr[j].w;
    }
    *(float4*)&wt[wrow][wcol8]     = wr0;
    *(float4*)&wt[wrow][wcol8 + 4] = wr1;
    __syncthreads();

    if (c + 1 < nchunk) {                   // prefetch next chunk
      const int ko = (c + 1) * KB;
#pragma unroll
      for (int j = 0; j < 8; ++j)
        xr[j] = *(const float4*)(xg + (long)(32 * j) * DD + ko);
      wr0 = *(const float4*)(wg + (long)ko * NE);
      wr1 = *(const float4*)(wg + (long)ko * NE + 4);
    }

#pragma unroll
    for (int kk = 0; kk < KB; ++kk) {
      const float4 x0 = *(const float4*)&xs[kk][xoff];
      const float4 x1 = *(const float4*)&xs[kk][xoff + 4];
      const float4 w0 = *(const float4*)&wt[kk][eoff];
      const float4 w1 = *(const float4*)&wt[kk][eoff + 4];
      const float xv[8] = {x0.x, x0.y, x0.z, x0.w, x1.x, x1.y, x1.z, x1.w};
      const float wv[8] = {w0.x, w0.y, w0.z, w0.w, w1.x, w1.y, w1.z, w1.w};
#pragma unroll
      for (int i = 0; i < 8; ++i)
#pragma unroll
        for (int j = 0; j < 8; ++j) acc[i][j] += xv[i] * wv[j];
    }
    __syncthreads();
  }

  // store partials: 8 token rows x 8 experts, b128 x2 per row (coalesced: eg fast)
  float* pb = part + ((long)s * TOKENS + t0 + xoff) * NE + eoff;
#pragma unroll
  for (int i = 0; i < 8; ++i) {
    float* pr = pb + (long)i * NE;
    *(float4*)(pr)     = make_float4(acc[i][0], acc[i][1], acc[i][2], acc[i][3]);
    *(float4*)(pr + 4) = make_float4(acc[i][4], acc[i][5], acc[i][6], acc[i][7]);
  }
}

// ---- k2: reduce partials + softmax + top-2 + outputs ----
__global__ __launch_bounds__(256)
void k2_finish(const float* __restrict__ part, int S, float* __restrict__ out) {
  const int tid  = threadIdx.x;
  const int lane = tid & 63;
  const int wv   = tid >> 6;
  const long t   = (long)blockIdx.x * 4 + wv;

  const float* p = part + t * NE + lane;
  float logit = 0.f;
  for (int s = 0; s < S; ++s) logit += p[(long)s * TOKENS * NE];

  out[4 * TOKENS + t * NE + lane] = logit;  // logits region

  // argmax (tie -> lowest index, matches jax.lax.top_k)
  float v = logit; int i = lane;
#pragma unroll
  for (int off = 32; off; off >>= 1) {
    float ov = __shfl_xor(v, off);
    int   oi = __shfl_xor(i, off);
    if (ov > v || (ov == v && oi < i)) { v = ov; i = oi; }
  }
  const float m = v; const int i1 = i;

  float vv = (lane == i1) ? -INFINITY : logit; int ii = lane;
#pragma unroll
  for (int off = 32; off; off >>= 1) {
    float ov = __shfl_xor(vv, off);
    int   oi = __shfl_xor(ii, off);
    if (ov > vv || (ov == vv && oi < ii)) { vv = ov; ii = oi; }
  }
  const int i2 = ii;

  float z = expf(logit - m);
  float Z = z;
#pragma unroll
  for (int off = 32; off; off >>= 1) Z += __shfl_xor(Z, off);

  float p1 = __shfl(z, i1) / Z;
  float p2 = __shfl(z, i2) / Z;

  if (lane == 0) {
    float denom = p1 + p2 + 1e-9f;
    out[t * 2 + 0] = (float)i1;               // indices [0, 2T)
    out[t * 2 + 1] = (float)i2;
    out[2 * TOKENS + t * 2 + 0] = p1 / denom; // weights [2T, 4T)
    out[2 * TOKENS + t * 2 + 1] = p2 / denom;
  }
}

extern "C" void kernel_launch(void* const* d_in, const int* in_sizes, int n_in,
                              void* d_out, int out_size, void* d_ws, size_t ws_size,
                              hipStream_t stream) {
  const float* x  = (const float*)d_in[0];
  const float* Wg = (const float*)d_in[1];
  float* out = (float*)d_out;

  float* WT = (float*)d_ws;
  const size_t wtBytes    = (size_t)DD * NE * sizeof(float);      // 1 MB
  const size_t sliceBytes = (size_t)TOKENS * NE * sizeof(float);  // 4.19 MB

  int S = 8;
  while (S > 1 && wtBytes + (size_t)S * sliceBytes > ws_size) S >>= 1;
  float* part = (float*)((char*)d_ws + wtBytes);
  if (wtBytes + sliceBytes > ws_size) {      // degenerate tiny-ws fallback
    S = 1;
    part = out + 4 * TOKENS;                 // logits region doubles as partials
  }
  const int kPerSlice = DD / S;              // divisible by KB for S in {1..8}

  k0_transpose<<<dim3(DD / 64), 256, 0, stream>>>(Wg, WT);
  k1_gemm<<<dim3((TOKENS / MBLK) * S), 256, 0, stream>>>(x, WT, part, kPerSlice);
  k2_finish<<<dim3(TOKENS / 4), 256, 0, stream>>>(part, S, out);
}

// Round 4
// 410.045 us; speedup vs baseline: 1.3301x; 1.3301x over previous
//
#include <hip/hip_runtime.h>
#include <math.h>

#define TOKENS 16384
#define DD 4096
#define NE 64
#define MBLK 256      // tokens per k1 block
#define KB 16         // k-chunk

// async global->LDS, 16B per lane, LDS dest = uniform base + lane*16
#define GLDS16(gp, lp) __builtin_amdgcn_global_load_lds((gp), (lp), 16, 0, 0)

// ---- k0: transpose W[e][k] -> WT[k][e] (1 MB, once per launch) ----
__global__ void k0_transpose(const float* __restrict__ Wg, float* __restrict__ WT) {
  const int k0 = blockIdx.x * 64;
  const int e  = threadIdx.x & 63;
  const int kq = threadIdx.x >> 6;          // 0..3
#pragma unroll
  for (int kk = 0; kk < 16; ++kk) {
    const int k = k0 + kq * 16 + kk;
    WT[(long)k * NE + e] = Wg[(long)e * DD + k];
  }
}

// ---- k1: register-tiled fp32 GEMM, global_load_lds double-buffered ----
// x tile [tok][16k] XOR-swizzled (key=((tok>>3)&3)<<2, both sides); W tile [16k][64e].
__global__ __launch_bounds__(256) __attribute__((amdgpu_waves_per_eu(2, 2)))
void k1_gemm(const float* __restrict__ x, const float* __restrict__ WT,
             float* __restrict__ part, int kPerSlice) {
  __shared__ __align__(16) float xs[2][MBLK * KB];  // 2 x 16 KB
  __shared__ __align__(16) float wt[2][KB * NE];    // 2 x 4 KB

  const int nm   = TOKENS / MBLK;           // 64
  const int mblk = blockIdx.x % nm;
  const int s    = blockIdx.x / nm;
  const int tid  = threadIdx.x;
  const int lane = tid & 63;
  const int wid  = tid >> 6;
  const long t0  = (long)mblk * MBLK;
  const int k0   = s * kPerSlice;

  // compute mapping: lane -> 8 tokens x 8 experts
  const int eg      = lane & 7;
  const int tg      = lane >> 3;
  const int tokbase = wid * 64 + tg * 8;    // +i, i=0..7
  const int eoff    = eg * 8;
  const int xkey    = tg & 3;               // read-side slot XOR

  // staging mapping: wave stages x segs wid*4..+3 (1KB each) + 1KB of W
  const float* gxs[4];
#pragma unroll
  for (int j = 0; j < 4; ++j) {
    const int tok = (wid * 4 + j) * 16 + (lane >> 2);
    const int kk  = ((lane & 3) << 2) ^ (((tok >> 3) & 3) << 2);  // src pre-swizzle
    gxs[j] = x + (t0 + tok) * (long)DD + k0 + kk;
  }
  const float* gw = WT + (long)(k0 + wid * 4 + (lane >> 4)) * NE + (lane & 15) * 4;

  float acc[8][8];
#pragma unroll
  for (int i = 0; i < 8; ++i)
#pragma unroll
    for (int j = 0; j < 8; ++j) acc[i][j] = 0.f;

  const int nchunk = kPerSlice / KB;

  // prologue: stage chunk 0 -> buf 0
#pragma unroll
  for (int j = 0; j < 4; ++j) GLDS16(gxs[j], &xs[0][(wid * 4 + j) * 256]);
  GLDS16(gw, &wt[0][wid * 256]);

  int cur = 0;
  for (int c = 0; c < nchunk; ++c) {
    __syncthreads();   // drains stage(c) into buf cur (vmcnt(0) at barrier)

    if (c + 1 < nchunk) {                   // issue stage(c+1) -> other buf
      const int nb = cur ^ 1;
      const long go = (long)(c + 1) * KB;
#pragma unroll
      for (int j = 0; j < 4; ++j)
        GLDS16(gxs[j] + go, &xs[nb][(wid * 4 + j) * 256]);
      GLDS16(gw + go * NE, &wt[nb][wid * 256]);
    }

    // compute chunk c (k ascending: kk = kkc*4+m)
#pragma unroll
    for (int kkc = 0; kkc < 4; ++kkc) {
      float4 xv[8];
#pragma unroll
      for (int i = 0; i < 8; ++i)
        xv[i] = *(const float4*)&xs[cur][(tokbase + i) * KB + ((kkc ^ xkey) << 2)];
#pragma unroll
      for (int m = 0; m < 4; ++m) {
        const int kk = kkc * 4 + m;
        const float4 w0 = *(const float4*)&wt[cur][kk * NE + eoff];
        const float4 w1 = *(const float4*)&wt[cur][kk * NE + eoff + 4];
#pragma unroll
        for (int i = 0; i < 8; ++i) {
          const float xm = (&xv[i].x)[m];
          acc[i][0] += xm * w0.x; acc[i][1] += xm * w0.y;
          acc[i][2] += xm * w0.z; acc[i][3] += xm * w0.w;
          acc[i][4] += xm * w1.x; acc[i][5] += xm * w1.y;
          acc[i][6] += xm * w1.z; acc[i][7] += xm * w1.w;
        }
      }
    }
    cur ^= 1;
  }

  // store partials (eg fast -> coalesced 256B rows)
  float* pb = part + ((long)s * TOKENS + t0 + tokbase) * NE + eoff;
#pragma unroll
  for (int i = 0; i < 8; ++i) {
    float* pr = pb + (long)i * NE;
    *(float4*)(pr)     = make_float4(acc[i][0], acc[i][1], acc[i][2], acc[i][3]);
    *(float4*)(pr + 4) = make_float4(acc[i][4], acc[i][5], acc[i][6], acc[i][7]);
  }
}

// ---- k2: reduce partials + softmax + top-2 + outputs ----
__global__ __launch_bounds__(256)
void k2_finish(const float* __restrict__ part, int S, float* __restrict__ out) {
  const int tid  = threadIdx.x;
  const int lane = tid & 63;
  const int wv   = tid >> 6;
  const long t   = (long)blockIdx.x * 4 + wv;

  const float* p = part + t * NE + lane;
  float logit = 0.f;
  for (int s = 0; s < S; ++s) logit += p[(long)s * TOKENS * NE];

  out[4 * TOKENS + t * NE + lane] = logit;  // logits region

  // argmax (tie -> lowest index, matches jax.lax.top_k)
  float v = logit; int i = lane;
#pragma unroll
  for (int off = 32; off; off >>= 1) {
    float ov = __shfl_xor(v, off);
    int   oi = __shfl_xor(i, off);
    if (ov > v || (ov == v && oi < i)) { v = ov; i = oi; }
  }
  const float m = v; const int i1 = i;

  float vv = (lane == i1) ? -INFINITY : logit; int ii = lane;
#pragma unroll
  for (int off = 32; off; off >>= 1) {
    float ov = __shfl_xor(vv, off);
    int   oi = __shfl_xor(ii, off);
    if (ov > vv || (ov == vv && oi < ii)) { vv = ov; ii = oi; }
  }
  const int i2 = ii;

  float z = expf(logit - m);
  float Z = z;
#pragma unroll
  for (int off = 32; off; off >>= 1) Z += __shfl_xor(Z, off);

  float p1 = __shfl(z, i1) / Z;
  float p2 = __shfl(z, i2) / Z;

  if (lane == 0) {
    float denom = p1 + p2 + 1e-9f;
    out[t * 2 + 0] = (float)i1;               // indices [0, 2T)
    out[t * 2 + 1] = (float)i2;
    out[2 * TOKENS + t * 2 + 0] = p1 / denom; // weights [2T, 4T)
    out[2 * TOKENS + t * 2 + 1] = p2 / denom;
  }
}

extern "C" void kernel_launch(void* const* d_in, const int* in_sizes, int n_in,
                              void* d_out, int out_size, void* d_ws, size_t ws_size,
                              hipStream_t stream) {
  const float* x  = (const float*)d_in[0];
  const float* Wg = (const float*)d_in[1];
  float* out = (float*)d_out;

  float* WT = (float*)d_ws;
  const size_t wtBytes    = (size_t)DD * NE * sizeof(float);      // 1 MB
  const size_t sliceBytes = (size_t)TOKENS * NE * sizeof(float);  // 4.19 MB

  int S = 8;
  while (S > 1 && wtBytes + (size_t)S * sliceBytes > ws_size) S >>= 1;
  float* part = (float*)((char*)d_ws + wtBytes);
  if (wtBytes + sliceBytes > ws_size) {      // degenerate tiny-ws fallback
    S = 1;
    part = out + 4 * TOKENS;                 // logits region doubles as partials
  }
  const int kPerSlice = DD / S;              // divisible by KB for S in {1..8}

  k0_transpose<<<dim3(DD / 64), 256, 0, stream>>>(Wg, WT);
  k1_gemm<<<dim3((TOKENS / MBLK) * S), 256, 0, stream>>>(x, WT, part, kPerSlice);
  k2_finish<<<dim3(TOKENS / 4), 256, 0, stream>>>(part, S, out);
}

// Round 7
// 406.836 us; speedup vs baseline: 1.3406x; 1.0079x over previous
//
#include <hip/hip_runtime.h>
#include <math.h>

#define TOKENS 16384
#define DD 4096
#define NE 64
#define MBLK 128      // tokens per k1 block
#define KB 16         // k-chunk

// async global->LDS, 16B per lane, LDS dest = uniform base + lane*16
#define GLDS16(gp, lp) __builtin_amdgcn_global_load_lds((gp), (lp), 16, 0, 0)

// ---- k0: transpose W[e][k] -> WT[k][e] (1 MB, once per launch) ----
__global__ void k0_transpose(const float* __restrict__ Wg, float* __restrict__ WT) {
  const int k0 = blockIdx.x * 64;
  const int e  = threadIdx.x & 63;
  const int kq = threadIdx.x >> 6;          // 0..3
#pragma unroll
  for (int kk = 0; kk < 16; ++kk) {
    const int k = k0 + kq * 16 + kk;
    WT[(long)k * NE + e] = Wg[(long)e * DD + k];
  }
}

// ---- k1: fp32 GEMM, 4 tok x 8 exp per lane, gload_lds dbuf, 4 blocks/CU ----
__global__ __launch_bounds__(256, 4)
void k1_gemm(const float* __restrict__ x, const float* __restrict__ WT,
             float* __restrict__ part, int kPerSlice) {
  __shared__ __align__(16) float xs[2][MBLK * KB];  // 2 x 8 KB
  __shared__ __align__(16) float wt[2][KB * NE];    // 2 x 4 KB

  const int nm   = TOKENS / MBLK;           // 128
  const int mblk = blockIdx.x % nm;
  const int s    = blockIdx.x / nm;
  const int tid  = threadIdx.x;
  const int lane = tid & 63;
  const int wid  = tid >> 6;
  const long t0  = (long)mblk * MBLK;
  const int k0   = s * kPerSlice;

  // compute mapping: lane -> 4 tokens x 8 experts
  const int eg   = lane & 7;
  const int tg   = lane >> 3;
  const int tokb = wid * 32 + tg * 4;       // +i, i=0..3
  const int eoff = eg * 8;
  const int xkey = tg & 3;                  // read-side slot XOR

  // x staging: wave stages 2 segs of 16 tokens (1KB each); both-sides swizzle
  const float* gxs[2];
#pragma unroll
  for (int q = 0; q < 2; ++q) {
    const int tok = (wid * 2 + q) * 16 + (lane >> 2);
    const int kk  = ((lane & 3) ^ ((tok >> 2) & 3)) << 2;   // src pre-swizzle
    gxs[q] = x + (t0 + tok) * (long)DD + k0 + kk;
  }
  // W staging: 1 GLDS16 per thread covers the 4KB chunk (linear)
  const float* gw = WT + (long)(k0 + wid * 4 + (lane >> 4)) * NE + (lane & 15) * 4;

  float acc[4][8];
#pragma unroll
  for (int i = 0; i < 4; ++i)
#pragma unroll
    for (int j = 0; j < 8; ++j) acc[i][j] = 0.f;

  const int nchunk = kPerSlice / KB;

  // prologue: stage chunk 0 -> buf 0
#pragma unroll
  for (int q = 0; q < 2; ++q) GLDS16(gxs[q], &xs[0][(wid * 2 + q) * 256]);
  GLDS16(gw, &wt[0][wid * 256]);

  int cur = 0;
  for (int c = 0; c < nchunk; ++c) {
    __syncthreads();   // vmcnt(0) drain: buf cur ready

    if (c + 1 < nchunk) {                   // issue stage(c+1) -> other buf
      const int nb = cur ^ 1;
      const long go = (long)(c + 1) * KB;
#pragma unroll
      for (int q = 0; q < 2; ++q)
        GLDS16(gxs[q] + go, &xs[nb][(wid * 2 + q) * 256]);
      GLDS16(gw + go * NE, &wt[nb][wid * 256]);
    }

    // compute chunk c (k ascending: kk = kkc*4+m)
#pragma unroll
    for (int kkc = 0; kkc < 4; ++kkc) {
      float4 xv[4];
#pragma unroll
      for (int i = 0; i < 4; ++i)
        xv[i] = *(const float4*)&xs[cur][(tokb + i) * KB + ((kkc ^ xkey) << 2)];
#pragma unroll
      for (int m = 0; m < 4; ++m) {
        const int kk = kkc * 4 + m;
        const float4 w0 = *(const float4*)&wt[cur][kk * NE + eoff];
        const float4 w1 = *(const float4*)&wt[cur][kk * NE + eoff + 4];
#pragma unroll
        for (int i = 0; i < 4; ++i) {
          const float xm = (&xv[i].x)[m];
          acc[i][0] += xm * w0.x; acc[i][1] += xm * w0.y;
          acc[i][2] += xm * w0.z; acc[i][3] += xm * w0.w;
          acc[i][4] += xm * w1.x; acc[i][5] += xm * w1.y;
          acc[i][6] += xm * w1.z; acc[i][7] += xm * w1.w;
        }
      }
    }
    cur ^= 1;
  }

  // store partials (eg fast -> coalesced 256B rows)
  float* pb = part + ((long)s * TOKENS + t0 + tokb) * NE + eoff;
#pragma unroll
  for (int i = 0; i < 4; ++i) {
    float* pr = pb + (long)i * NE;
    *(float4*)(pr)     = make_float4(acc[i][0], acc[i][1], acc[i][2], acc[i][3]);
    *(float4*)(pr + 4) = make_float4(acc[i][4], acc[i][5], acc[i][6], acc[i][7]);
  }
}

// ---- k2: reduce partials + softmax + top-2 + outputs ----
__global__ __launch_bounds__(256)
void k2_finish(const float* __restrict__ part, int S, float* __restrict__ out) {
  const int tid  = threadIdx.x;
  const int lane = tid & 63;
  const int wv   = tid >> 6;
  const long t   = (long)blockIdx.x * 4 + wv;

  const float* p = part + t * NE + lane;
  float logit = 0.f;
  for (int s = 0; s < S; ++s) logit += p[(long)s * TOKENS * NE];

  out[4 * TOKENS + t * NE + lane] = logit;  // logits region

  // argmax (tie -> lowest index, matches jax.lax.top_k)
  float v = logit; int i = lane;
#pragma unroll
  for (int off = 32; off; off >>= 1) {
    float ov = __shfl_xor(v, off);
    int   oi = __shfl_xor(i, off);
    if (ov > v || (ov == v && oi < i)) { v = ov; i = oi; }
  }
  const float m = v; const int i1 = i;

  float vv = (lane == i1) ? -INFINITY : logit; int ii = lane;
#pragma unroll
  for (int off = 32; off; off >>= 1) {
    float ov = __shfl_xor(vv, off);
    int   oi = __shfl_xor(ii, off);
    if (ov > vv || (ov == vv && oi < ii)) { vv = ov; ii = oi; }
  }
  const int i2 = ii;

  float z = expf(logit - m);
  float Z = z;
#pragma unroll
  for (int off = 32; off; off >>= 1) Z += __shfl_xor(Z, off);

  float p1 = __shfl(z, i1) / Z;
  float p2 = __shfl(z, i2) / Z;

  if (lane == 0) {
    float denom = p1 + p2 + 1e-9f;
    out[t * 2 + 0] = (float)i1;               // indices [0, 2T)
    out[t * 2 + 1] = (float)i2;
    out[2 * TOKENS + t * 2 + 0] = p1 / denom; // weights [2T, 4T)
    out[2 * TOKENS + t * 2 + 1] = p2 / denom;
  }
}

extern "C" void kernel_launch(void* const* d_in, const int* in_sizes, int n_in,
                              void* d_out, int out_size, void* d_ws, size_t ws_size,
                              hipStream_t stream) {
  const float* x  = (const float*)d_in[0];
  const float* Wg = (const float*)d_in[1];
  float* out = (float*)d_out;

  float* WT = (float*)d_ws;
  const size_t wtBytes    = (size_t)DD * NE * sizeof(float);      // 1 MB
  const size_t sliceBytes = (size_t)TOKENS * NE * sizeof(float);  // 4.19 MB

  int S = 8;
  while (S > 1 && wtBytes + (size_t)S * sliceBytes > ws_size) S >>= 1;
  float* part = (float*)((char*)d_ws + wtBytes);
  if (wtBytes + sliceBytes > ws_size) {      // degenerate tiny-ws fallback
    S = 1;
    part = out + 4 * TOKENS;                 // logits region doubles as partials
  }
  const int kPerSlice = DD / S;              // divisible by KB for S in {1..8}

  k0_transpose<<<dim3(DD / 64), 256, 0, stream>>>(Wg, WT);
  k1_gemm<<<dim3((TOKENS / MBLK) * S), 256, 0, stream>>>(x, WT, part, kPerSlice);
  k2_finish<<<dim3(TOKENS / 4), 256, 0, stream>>>(part, S, out);
}